// Round 2
// baseline (351.231 us; speedup 1.0000x reference)
//
#include <hip/hip_runtime.h>
#include <math.h>

#define NPIX 4096

// ---------------------------------------------------------------------------
// DPP-based 64-lane inclusive scan (VALU only, no LDS traffic)
// ---------------------------------------------------------------------------
template <int CTRL, int RM>
__device__ __forceinline__ float dpp_add(float x) {
    int xi = __builtin_bit_cast(int, x);
    int sh = __builtin_amdgcn_update_dpp(0, xi, CTRL, RM, 0xf, false);
    return x + __builtin_bit_cast(float, sh);
}

__device__ __forceinline__ float wave_iscan(float x) {
    x = dpp_add<0x111, 0xf>(x);   // row_shr:1
    x = dpp_add<0x112, 0xf>(x);   // row_shr:2
    x = dpp_add<0x114, 0xf>(x);   // row_shr:4
    x = dpp_add<0x118, 0xf>(x);   // row_shr:8
    x = dpp_add<0x142, 0xa>(x);   // row_bcast:15 -> rows 1,3
    x = dpp_add<0x143, 0xc>(x);   // row_bcast:31 -> rows 2,3
    return x;
}

// ---------------------------------------------------------------------------
// Kernel 1: fused QKV 1x1-conv GEMM (unchanged from R1).
// ---------------------------------------------------------------------------
__global__ __launch_bounds__(256) void qkv_kernel(
    const float* __restrict__ x, const float* __restrict__ Wq,
    const float* __restrict__ Wk, const float* __restrict__ Wv,
    float* __restrict__ qo, float* __restrict__ ko, float* __restrict__ vo)
{
    const int pt = blockIdx.x * 128;
    const int ot = blockIdx.y * 32;
    const int mat = blockIdx.z;
    const float* __restrict__ W = (mat == 0) ? Wq : ((mat == 1) ? Wk : Wv);
    float* __restrict__ out = (mat == 0) ? qo : ((mat == 1) ? ko : vo);

    __shared__ float Xs[32][132];
    __shared__ float Ws[32][33];

    const int t = threadIdx.x;
    const int pc = t & 31;
    const int oc = t >> 5;

    float acc[4][4];
#pragma unroll
    for (int j = 0; j < 4; j++)
#pragma unroll
        for (int i = 0; i < 4; i++) acc[j][i] = 0.f;

    for (int kt = 0; kt < 256; kt += 32) {
#pragma unroll
        for (int i = 0; i < 4; i++) {
            int idx = t + (i << 8);
            int c = idx >> 5;
            int p4 = (idx & 31) << 2;
            float4 val = *reinterpret_cast<const float4*>(x + (kt + c) * NPIX + pt + p4);
            *reinterpret_cast<float4*>(&Xs[c][p4]) = val;
        }
#pragma unroll
        for (int i = 0; i < 4; i++) {
            int idx = t + (i << 8);
            int o = idx >> 5;
            int c = idx & 31;
            Ws[o][c] = W[(ot + o) * 256 + kt + c];
        }
        __syncthreads();
#pragma unroll
        for (int kk = 0; kk < 32; kk++) {
            float4 a = *reinterpret_cast<const float4*>(&Xs[kk][pc << 2]);
            float av[4] = {a.x, a.y, a.z, a.w};
            float bv[4];
#pragma unroll
            for (int j = 0; j < 4; j++) bv[j] = Ws[(oc << 2) + j][kk];
#pragma unroll
            for (int j = 0; j < 4; j++)
#pragma unroll
                for (int i = 0; i < 4; i++)
                    acc[j][i] = fmaf(bv[j], av[i], acc[j][i]);
        }
        __syncthreads();
    }

    if (mat < 2) {
#pragma unroll
        for (int j = 0; j < 4; j++) {
            const int o = ot + (oc << 2) + j;
            float4 r;
            r.x = 1.f / (1.f + __expf(-acc[j][0]));
            r.y = 1.f / (1.f + __expf(-acc[j][1]));
            r.z = 1.f / (1.f + __expf(-acc[j][2]));
            r.w = 1.f / (1.f + __expf(-acc[j][3]));
            *reinterpret_cast<float4*>(out + o * NPIX + pt + (pc << 2)) = r;
        }
    } else {
        float* scratch = &Ws[0][0];
#pragma unroll
        for (int i = 0; i < 4; i++) {
            float ss = 0.f;
#pragma unroll
            for (int j = 0; j < 4; j++) ss += acc[j][i] * acc[j][i];
            scratch[oc * 128 + (pc << 2) + i] = ss;
        }
        __syncthreads();
        float scale[4];
#pragma unroll
        for (int i = 0; i < 4; i++) {
            float tot = 0.f;
#pragma unroll
            for (int g = 0; g < 8; g++) tot += scratch[g * 128 + (pc << 2) + i];
            scale[i] = 1.f / fmaxf(sqrtf(tot), 1e-12f);
        }
#pragma unroll
        for (int j = 0; j < 4; j++) {
            const int o = ot + (oc << 2) + j;
            float4 r;
            r.x = acc[j][0] * scale[0];
            r.y = acc[j][1] * scale[1];
            r.z = acc[j][2] * scale[2];
            r.w = acc[j][3] * scale[3];
            *reinterpret_cast<float4*>(out + o * NPIX + pt + (pc << 2)) = r;
        }
    }
}

// ---------------------------------------------------------------------------
// Kernel 2: per-(head, f, d-group) fused integral-image + windowed contraction.
// Integral image stored TRANSPOSED: Pt[x][yp], yp = 32 + logical_y.
//   yp 0..32  : zeros (logical y <= 0)          [persistent]
//   yp 33..96 : integral rows y = 1..64         [rewritten per d]
//   yp 97..127: replicated bottom row (y > 64)  [rewritten per d]
//   Pt[0][*] = 0 (logical x = 0 column)         [persistent]
// Row scans & column scans via DPP in registers; corner gathers are aligned
// float4 reads along y serving 4 pixels at once.
// ---------------------------------------------------------------------------
template <int PD>
__global__ __launch_bounds__(256, 4) void attn_kernel(
    const float* __restrict__ q, const float* __restrict__ k,
    const float* __restrict__ v, float* __restrict__ num, float* __restrict__ nrm)
{
    const int f = blockIdx.x;          // 0..32 (32 == norm slot)
    const int head = blockIdx.y;       // 0..7
    const int dg = blockIdx.z;         // 0..(32/PD - 1)
    const bool isnorm = (f == 32);

    const float* __restrict__ kh = k + (head * 32 + dg * PD) * NPIX;
    const float* __restrict__ qh = q + (head * 32 + dg * PD) * NPIX;
    const float* __restrict__ vf = v + (head * 32 + (isnorm ? 0 : f)) * NPIX;

    __shared__ __align__(16) float Pt[65][132];   // 34,320 B

    const int t = threadIdx.x;
    const int lane = t & 63;
    const int wv = t >> 6;

    // zero-init whole tile once; yp<=32 and xs==0 stay zero forever
    for (int i = t; i < 65 * 132; i += 256) (&Pt[0][0])[i] = 0.f;

    float vreg[16];
#pragma unroll
    for (int rr = 0; rr < 16; rr++)
        vreg[rr] = isnorm ? 1.f : vf[(wv * 16 + rr) * 64 + lane];

    float acc[3][16];
#pragma unroll
    for (int w = 0; w < 3; w++)
#pragma unroll
        for (int i = 0; i < 16; i++) acc[w][i] = 0.f;

    __syncthreads();

    for (int dd = 0; dd < PD; dd++) {
        const float* __restrict__ kd = kh + dd * NPIX;
        // phase 1: row scans (wave wv owns rows wv*16..wv*16+15), transposed store
#pragma unroll
        for (int rr = 0; rr < 16; rr++) {
            const int r = wv * 16 + rr;
            float run = kd[r * 64 + lane] * vreg[rr];
            run = wave_iscan(run);
            Pt[lane + 1][33 + r] = run;          // P[r+1][lane+1]
        }
        __syncthreads();
        // phase 2: column scans (16 columns per wave) + bottom replicate pad
#pragma unroll
        for (int cc = 0; cc < 16; cc++) {
            const int xs = 1 + wv * 16 + cc;
            float run = Pt[xs][33 + lane];       // contiguous: conflict-free
            run = wave_iscan(run);
            Pt[xs][33 + lane] = run;
            float tot = __builtin_bit_cast(float,
                __builtin_amdgcn_readlane(__builtin_bit_cast(int, run), 63));
            if (lane < 31) Pt[xs][97 + lane] = tot;
        }
        __syncthreads();
        // phase 4: windowed box-diff contraction, float4 corner reads
        const float* __restrict__ qd = qh + dd * NPIX;
#pragma unroll
        for (int i = 0; i < 4; i++) {
            const int y0 = i * 16 + wv * 4;      // pixel rows y0..y0+3, x = lane
            float qv[4];
#pragma unroll
            for (int j = 0; j < 4; j++) qv[j] = qd[(y0 + j) * 64 + lane];
#pragma unroll
            for (int w = 0; w < 3; w++) {
                const int hw = 32 >> w;
                const int xlo = max(lane - hw, 0);
                const int xhi = min(lane + hw, 64);
                const int ylo = 32 + y0 - hw;    // physical, pad absorbs clamp
                const int yhi = 32 + y0 + hw;
                float4 A4 = *reinterpret_cast<const float4*>(&Pt[xhi][yhi]);
                float4 B4 = *reinterpret_cast<const float4*>(&Pt[xlo][yhi]);
                float4 C4, E4;
                if (y0 + 3 <= hw) {              // wave-uniform: whole quad in zero pad
                    C4 = make_float4(0.f, 0.f, 0.f, 0.f);
                    E4 = C4;
                } else {
                    C4 = *reinterpret_cast<const float4*>(&Pt[xhi][ylo]);
                    E4 = *reinterpret_cast<const float4*>(&Pt[xlo][ylo]);
                }
                acc[w][i * 4 + 0] = fmaf(qv[0], (A4.x - B4.x) - (C4.x - E4.x), acc[w][i * 4 + 0]);
                acc[w][i * 4 + 1] = fmaf(qv[1], (A4.y - B4.y) - (C4.y - E4.y), acc[w][i * 4 + 1]);
                acc[w][i * 4 + 2] = fmaf(qv[2], (A4.z - B4.z) - (C4.z - E4.z), acc[w][i * 4 + 2]);
                acc[w][i * 4 + 3] = fmaf(qv[3], (A4.w - B4.w) - (C4.w - E4.w), acc[w][i * 4 + 3]);
            }
        }
        __syncthreads();
    }

    // epilogue: write this d-group's partial sums
    float* __restrict__ nout = num + (size_t)dg * 3145728;
    float* __restrict__ rout = nrm + (size_t)dg * 98304;
#pragma unroll
    for (int w = 0; w < 3; w++) {
#pragma unroll
        for (int i = 0; i < 4; i++) {
#pragma unroll
            for (int j = 0; j < 4; j++) {
                const int px = (i * 16 + wv * 4 + j) * 64 + lane;
                const float val = acc[w][i * 4 + j];
                if (isnorm) rout[(w * 8 + head) * NPIX + px] = val;
                else        nout[((w * 8 + head) * 32 + f) * NPIX + px] = val;
            }
        }
    }
}

// ---------------------------------------------------------------------------
// Kernel 3: merge d-group partials: A = (sum_s num_s) / (sum_s nrm_s + 1e-6).
// grid (4, 24), 256 threads, float4 per thread.
// ---------------------------------------------------------------------------
template <int NS>
__global__ __launch_bounds__(256) void merge_kernel(
    const float* __restrict__ num, const float* __restrict__ nrm,
    float* __restrict__ A)
{
    const int wh = blockIdx.y;                                   // 0..23
    const int p4 = (blockIdx.x * 256 + threadIdx.x) * 4;
    float nx = 0.f, ny = 0.f, nz = 0.f, nw = 0.f;
#pragma unroll
    for (int s = 0; s < NS; s++) {
        float4 nv = *reinterpret_cast<const float4*>(nrm + s * 98304 + wh * NPIX + p4);
        nx += nv.x; ny += nv.y; nz += nv.z; nw += nv.w;
    }
    const float rx = 1.f / (nx + 1e-6f), ry = 1.f / (ny + 1e-6f);
    const float rz = 1.f / (nz + 1e-6f), rw = 1.f / (nw + 1e-6f);
    for (int ff = 0; ff < 32; ff++) {
        float ax = 0.f, ay = 0.f, az = 0.f, aw = 0.f;
#pragma unroll
        for (int s = 0; s < NS; s++) {
            float4 tv = *reinterpret_cast<const float4*>(
                num + (size_t)s * 3145728 + (wh * 32 + ff) * NPIX + p4);
            ax += tv.x; ay += tv.y; az += tv.z; aw += tv.w;
        }
        float4 r = make_float4(ax * rx, ay * ry, az * rz, aw * rw);
        *reinterpret_cast<float4*>(A + (wh * 32 + ff) * NPIX + p4) = r;
    }
}

// ---------------------------------------------------------------------------
// Kernel 4: final 1x1 conv on merged A. grid (32 p-tiles, 8 o-tiles).
// ---------------------------------------------------------------------------
__global__ __launch_bounds__(256) void out_kernel(
    const float* __restrict__ A, const float* __restrict__ Wout,
    const float* __restrict__ bout, float* __restrict__ out)
{
    const int pt = blockIdx.x * 128;
    const int ot = blockIdx.y * 32;
    __shared__ float As[32][132];
    __shared__ float Ws[32][33];
    const int t = threadIdx.x;
    const int pc = t & 31;
    const int oc = t >> 5;

    float acc[4][4];
#pragma unroll
    for (int j = 0; j < 4; j++)
#pragma unroll
        for (int i = 0; i < 4; i++) acc[j][i] = 0.f;

    for (int kt = 0; kt < 24; kt++) {
        const float* __restrict__ At = A + (size_t)kt * 32 * NPIX;
#pragma unroll
        for (int i = 0; i < 4; i++) {
            int idx = t + (i << 8);
            int c = idx >> 5;
            int p4 = (idx & 31) << 2;
            *reinterpret_cast<float4*>(&As[c][p4]) =
                *reinterpret_cast<const float4*>(At + c * NPIX + pt + p4);
        }
#pragma unroll
        for (int i = 0; i < 4; i++) {
            int idx = t + (i << 8);
            int o = idx >> 5;
            int c = idx & 31;
            Ws[o][c] = Wout[(ot + o) * 768 + kt * 32 + c];
        }
        __syncthreads();
#pragma unroll
        for (int kk = 0; kk < 32; kk++) {
            float4 a = *reinterpret_cast<const float4*>(&As[kk][pc << 2]);
            float av[4] = {a.x, a.y, a.z, a.w};
            float bv[4];
#pragma unroll
            for (int j = 0; j < 4; j++) bv[j] = Ws[(oc << 2) + j][kk];
#pragma unroll
            for (int j = 0; j < 4; j++)
#pragma unroll
                for (int i = 0; i < 4; i++)
                    acc[j][i] = fmaf(bv[j], av[i], acc[j][i]);
        }
        __syncthreads();
    }

#pragma unroll
    for (int j = 0; j < 4; j++) {
        const int o = ot + (oc << 2) + j;
        const float bb = bout[o];
        float4 r;
        r.x = acc[j][0] + bb;
        r.y = acc[j][1] + bb;
        r.z = acc[j][2] + bb;
        r.w = acc[j][3] + bb;
        *reinterpret_cast<float4*>(out + o * NPIX + pt + (pc << 2)) = r;
    }
}

extern "C" void kernel_launch(void* const* d_in, const int* in_sizes, int n_in,
                              void* d_out, int out_size, void* d_ws, size_t ws_size,
                              hipStream_t stream)
{
    const float* x    = (const float*)d_in[0];
    const float* Wq   = (const float*)d_in[1];
    const float* Wk   = (const float*)d_in[2];
    const float* Wv   = (const float*)d_in[3];
    const float* Wout = (const float*)d_in[4];
    const float* bout = (const float*)d_in[5];
    float* out = (float*)d_out;

    float* ws = (float*)d_ws;
    float* q = ws;                    // 1,048,576 floats
    float* k = ws + 1048576;
    float* v = ws + 2097152;
    float* A = ws;                    // aliases q/k/v (dead after attn)
    float* num = ws + 3145728;        // NS x 3,145,728 partials
    const size_t fl = ws_size / 4;

    qkv_kernel<<<dim3(32, 8, 3), 256, 0, stream>>>(x, Wq, Wk, Wv, q, k, v);

    if (fl >= 16121856) {             // NS = 4
        float* nrm = num + (size_t)4 * 3145728;
        attn_kernel<8><<<dim3(33, 8, 4), 256, 0, stream>>>(q, k, v, num, nrm);
        merge_kernel<4><<<dim3(4, 24), 256, 0, stream>>>(num, nrm, A);
    } else if (fl >= 9633792) {       // NS = 2
        float* nrm = num + (size_t)2 * 3145728;
        attn_kernel<16><<<dim3(33, 8, 2), 256, 0, stream>>>(q, k, v, num, nrm);
        merge_kernel<2><<<dim3(4, 24), 256, 0, stream>>>(num, nrm, A);
    } else {                          // NS = 1
        float* nrm = num + (size_t)3145728;
        attn_kernel<32><<<dim3(33, 8, 1), 256, 0, stream>>>(q, k, v, num, nrm);
        merge_kernel<1><<<dim3(4, 24), 256, 0, stream>>>(num, nrm, A);
    }

    out_kernel<<<dim3(32, 8), 256, 0, stream>>>(A, Wout, bout, out);
}

// Round 3
// 216.549 us; speedup vs baseline: 1.6219x; 1.6219x over previous
//
#include <hip/hip_runtime.h>
#include <math.h>

#define NPIX 4096

// ---------------------------------------------------------------------------
// DPP-based 64-lane inclusive scan (VALU only, no LDS traffic)
// ---------------------------------------------------------------------------
template <int CTRL, int RM>
__device__ __forceinline__ float dpp_add(float x) {
    int xi = __builtin_bit_cast(int, x);
    int sh = __builtin_amdgcn_update_dpp(0, xi, CTRL, RM, 0xf, false);
    return x + __builtin_bit_cast(float, sh);
}

__device__ __forceinline__ float wave_iscan(float x) {
    x = dpp_add<0x111, 0xf>(x);   // row_shr:1
    x = dpp_add<0x112, 0xf>(x);   // row_shr:2
    x = dpp_add<0x114, 0xf>(x);   // row_shr:4
    x = dpp_add<0x118, 0xf>(x);   // row_shr:8
    x = dpp_add<0x142, 0xa>(x);   // row_bcast:15 -> rows 1,3
    x = dpp_add<0x143, 0xc>(x);   // row_bcast:31 -> rows 2,3
    return x;
}

// ---------------------------------------------------------------------------
// Kernel 1: fused QKV 1x1-conv GEMM. B-operand staged transposed (Wt[c][o],
// stride 36) so inner loop reads one broadcast float4 per kk.
// ---------------------------------------------------------------------------
__global__ __launch_bounds__(256) void qkv_kernel(
    const float* __restrict__ x, const float* __restrict__ Wq,
    const float* __restrict__ Wk, const float* __restrict__ Wv,
    float* __restrict__ qo, float* __restrict__ ko, float* __restrict__ vo)
{
    const int pt = blockIdx.x * 128;
    const int ot = blockIdx.y * 32;
    const int mat = blockIdx.z;
    const float* __restrict__ W = (mat == 0) ? Wq : ((mat == 1) ? Wk : Wv);
    float* __restrict__ out = (mat == 0) ? qo : ((mat == 1) ? ko : vo);

    __shared__ float Xs[32][132];
    __shared__ __align__(16) float Wt[32][36];   // [c][o]

    const int t = threadIdx.x;
    const int pc = t & 31;
    const int oc = t >> 5;

    float acc[4][4];
#pragma unroll
    for (int j = 0; j < 4; j++)
#pragma unroll
        for (int i = 0; i < 4; i++) acc[j][i] = 0.f;

    for (int kt = 0; kt < 256; kt += 32) {
#pragma unroll
        for (int i = 0; i < 4; i++) {
            int idx = t + (i << 8);
            int c = idx >> 5;
            int p4 = (idx & 31) << 2;
            float4 val = *reinterpret_cast<const float4*>(x + (kt + c) * NPIX + pt + p4);
            *reinterpret_cast<float4*>(&Xs[c][p4]) = val;
        }
#pragma unroll
        for (int i = 0; i < 4; i++) {
            int idx = t + (i << 8);
            int o = idx & 31;            // lanes walk o -> conflict-free writes
            int c = idx >> 5;
            Wt[c][o] = W[(ot + o) * 256 + kt + c];
        }
        __syncthreads();
#pragma unroll
        for (int kk = 0; kk < 32; kk++) {
            float4 a = *reinterpret_cast<const float4*>(&Xs[kk][pc << 2]);
            float av[4] = {a.x, a.y, a.z, a.w};
            float4 b4 = *reinterpret_cast<const float4*>(&Wt[kk][oc << 2]);
            float bv[4] = {b4.x, b4.y, b4.z, b4.w};
#pragma unroll
            for (int j = 0; j < 4; j++)
#pragma unroll
                for (int i = 0; i < 4; i++)
                    acc[j][i] = fmaf(bv[j], av[i], acc[j][i]);
        }
        __syncthreads();
    }

    if (mat < 2) {
#pragma unroll
        for (int j = 0; j < 4; j++) {
            const int o = ot + (oc << 2) + j;
            float4 r;
            r.x = 1.f / (1.f + __expf(-acc[j][0]));
            r.y = 1.f / (1.f + __expf(-acc[j][1]));
            r.z = 1.f / (1.f + __expf(-acc[j][2]));
            r.w = 1.f / (1.f + __expf(-acc[j][3]));
            *reinterpret_cast<float4*>(out + o * NPIX + pt + (pc << 2)) = r;
        }
    } else {
        float* scratch = &Xs[0][0];      // reuse; >=1024 floats
        __syncthreads();
#pragma unroll
        for (int i = 0; i < 4; i++) {
            float ss = 0.f;
#pragma unroll
            for (int j = 0; j < 4; j++) ss += acc[j][i] * acc[j][i];
            scratch[oc * 128 + (pc << 2) + i] = ss;
        }
        __syncthreads();
        float scale[4];
#pragma unroll
        for (int i = 0; i < 4; i++) {
            float tot = 0.f;
#pragma unroll
            for (int g = 0; g < 8; g++) tot += scratch[g * 128 + (pc << 2) + i];
            scale[i] = 1.f / fmaxf(sqrtf(tot), 1e-12f);
        }
#pragma unroll
        for (int j = 0; j < 4; j++) {
            const int o = ot + (oc << 2) + j;
            float4 r;
            r.x = acc[j][0] * scale[0];
            r.y = acc[j][1] * scale[1];
            r.z = acc[j][2] * scale[2];
            r.w = acc[j][3] * scale[3];
            *reinterpret_cast<float4*>(out + o * NPIX + pt + (pc << 2)) = r;
        }
    }
}

// ---------------------------------------------------------------------------
// Kernel 2: per-(head, f, d-group) fused integral-image + windowed contraction.
// Transposed integral storage Pt[x][yp], yp = 32 + logical_y:
//   yp 0..32 zeros (y<=0, persistent), 33..96 data (y=1..64, per d),
//   97..127 replicated bottom row (y>64, per d), Pt[0][*]=0 persistent.
// DPP scans in registers; corner gathers are aligned float4 reads along y.
// ONE-ARG launch_bounds: R2's (256,4) capped VGPRs at 64 -> acc spills ->
// 339 MB scratch writes. Do not re-add a min-occupancy hint here.
// ---------------------------------------------------------------------------
template <int PD>
__global__ __launch_bounds__(256) void attn_kernel(
    const float* __restrict__ q, const float* __restrict__ k,
    const float* __restrict__ v, float* __restrict__ num, float* __restrict__ nrm)
{
    const int f = blockIdx.x;          // 0..32 (32 == norm slot)
    const int head = blockIdx.y;       // 0..7
    const int dg = blockIdx.z;         // 0..(32/PD - 1)
    const bool isnorm = (f == 32);

    const float* __restrict__ kh = k + (head * 32 + dg * PD) * NPIX;
    const float* __restrict__ qh = q + (head * 32 + dg * PD) * NPIX;
    const float* __restrict__ vf = v + (head * 32 + (isnorm ? 0 : f)) * NPIX;

    __shared__ __align__(16) float Pt[65][132];   // 34,320 B

    const int t = threadIdx.x;
    const int lane = t & 63;
    const int wv = t >> 6;

    for (int i = t; i < 65 * 132; i += 256) (&Pt[0][0])[i] = 0.f;

    float vreg[16];
#pragma unroll
    for (int rr = 0; rr < 16; rr++)
        vreg[rr] = isnorm ? 1.f : vf[(wv * 16 + rr) * 64 + lane];

    float acc[3][16];
#pragma unroll
    for (int w = 0; w < 3; w++)
#pragma unroll
        for (int i = 0; i < 16; i++) acc[w][i] = 0.f;

    __syncthreads();

    for (int dd = 0; dd < PD; dd++) {
        const float* __restrict__ kd = kh + dd * NPIX;
        // phase 1: row scans, transposed store
#pragma unroll
        for (int rr = 0; rr < 16; rr++) {
            const int r = wv * 16 + rr;
            float run = kd[r * 64 + lane] * vreg[rr];
            run = wave_iscan(run);
            Pt[lane + 1][33 + r] = run;
        }
        __syncthreads();
        // phase 2: column scans + bottom replicate pad
#pragma unroll
        for (int cc = 0; cc < 16; cc++) {
            const int xs = 1 + wv * 16 + cc;
            float run = Pt[xs][33 + lane];
            run = wave_iscan(run);
            Pt[xs][33 + lane] = run;
            float tot = __builtin_bit_cast(float,
                __builtin_amdgcn_readlane(__builtin_bit_cast(int, run), 63));
            if (lane < 31) Pt[xs][97 + lane] = tot;
        }
        __syncthreads();
        // phase 4: windowed box-diff contraction, float4 corner reads
        const float* __restrict__ qd = qh + dd * NPIX;
#pragma unroll
        for (int i = 0; i < 4; i++) {
            const int y0 = i * 16 + wv * 4;
            float qv[4];
#pragma unroll
            for (int j = 0; j < 4; j++) qv[j] = qd[(y0 + j) * 64 + lane];
#pragma unroll
            for (int w = 0; w < 3; w++) {
                const int hw = 32 >> w;
                const int xlo = max(lane - hw, 0);
                const int xhi = min(lane + hw, 64);
                const int ylo = 32 + y0 - hw;
                const int yhi = 32 + y0 + hw;
                float4 A4 = *reinterpret_cast<const float4*>(&Pt[xhi][yhi]);
                float4 B4 = *reinterpret_cast<const float4*>(&Pt[xlo][yhi]);
                float4 C4, E4;
                if (y0 + 3 <= hw) {
                    C4 = make_float4(0.f, 0.f, 0.f, 0.f);
                    E4 = C4;
                } else {
                    C4 = *reinterpret_cast<const float4*>(&Pt[xhi][ylo]);
                    E4 = *reinterpret_cast<const float4*>(&Pt[xlo][ylo]);
                }
                acc[w][i * 4 + 0] = fmaf(qv[0], (A4.x - B4.x) - (C4.x - E4.x), acc[w][i * 4 + 0]);
                acc[w][i * 4 + 1] = fmaf(qv[1], (A4.y - B4.y) - (C4.y - E4.y), acc[w][i * 4 + 1]);
                acc[w][i * 4 + 2] = fmaf(qv[2], (A4.z - B4.z) - (C4.z - E4.z), acc[w][i * 4 + 2]);
                acc[w][i * 4 + 3] = fmaf(qv[3], (A4.w - B4.w) - (C4.w - E4.w), acc[w][i * 4 + 3]);
            }
        }
        __syncthreads();
    }

    float* __restrict__ nout = num + (size_t)dg * 3145728;
    float* __restrict__ rout = nrm + (size_t)dg * 98304;
#pragma unroll
    for (int w = 0; w < 3; w++) {
#pragma unroll
        for (int i = 0; i < 4; i++) {
#pragma unroll
            for (int j = 0; j < 4; j++) {
                const int px = (i * 16 + wv * 4 + j) * 64 + lane;
                const float val = acc[w][i * 4 + j];
                if (isnorm) rout[(w * 8 + head) * NPIX + px] = val;
                else        nout[((w * 8 + head) * 32 + f) * NPIX + px] = val;
            }
        }
    }
}

// ---------------------------------------------------------------------------
// Kernel 3: merge d-group partials: A = (sum_s num_s) / (sum_s nrm_s + 1e-6).
// ---------------------------------------------------------------------------
template <int NS>
__global__ __launch_bounds__(256) void merge_kernel(
    const float* __restrict__ num, const float* __restrict__ nrm,
    float* __restrict__ A)
{
    const int wh = blockIdx.y;
    const int p4 = (blockIdx.x * 256 + threadIdx.x) * 4;
    float nx = 0.f, ny = 0.f, nz = 0.f, nw = 0.f;
#pragma unroll
    for (int s = 0; s < NS; s++) {
        float4 nv = *reinterpret_cast<const float4*>(nrm + s * 98304 + wh * NPIX + p4);
        nx += nv.x; ny += nv.y; nz += nv.z; nw += nv.w;
    }
    const float rx = 1.f / (nx + 1e-6f), ry = 1.f / (ny + 1e-6f);
    const float rz = 1.f / (nz + 1e-6f), rw = 1.f / (nw + 1e-6f);
    for (int ff = 0; ff < 32; ff++) {
        float ax = 0.f, ay = 0.f, az = 0.f, aw = 0.f;
#pragma unroll
        for (int s = 0; s < NS; s++) {
            float4 tv = *reinterpret_cast<const float4*>(
                num + (size_t)s * 3145728 + (wh * 32 + ff) * NPIX + p4);
            ax += tv.x; ay += tv.y; az += tv.z; aw += tv.w;
        }
        float4 r = make_float4(ax * rx, ay * ry, az * rz, aw * rw);
        *reinterpret_cast<float4*>(A + (wh * 32 + ff) * NPIX + p4) = r;
    }
}

// ---------------------------------------------------------------------------
// Kernel 4: final 1x1 conv on merged A, B-operand transposed in LDS.
// ---------------------------------------------------------------------------
__global__ __launch_bounds__(256) void out_kernel(
    const float* __restrict__ A, const float* __restrict__ Wout,
    const float* __restrict__ bout, float* __restrict__ out)
{
    const int pt = blockIdx.x * 128;
    const int ot = blockIdx.y * 32;
    __shared__ float As[32][132];
    __shared__ __align__(16) float Wt[32][36];
    const int t = threadIdx.x;
    const int pc = t & 31;
    const int oc = t >> 5;

    float acc[4][4];
#pragma unroll
    for (int j = 0; j < 4; j++)
#pragma unroll
        for (int i = 0; i < 4; i++) acc[j][i] = 0.f;

    for (int kt = 0; kt < 24; kt++) {
        const float* __restrict__ At = A + (size_t)kt * 32 * NPIX;
#pragma unroll
        for (int i = 0; i < 4; i++) {
            int idx = t + (i << 8);
            int c = idx >> 5;
            int p4 = (idx & 31) << 2;
            *reinterpret_cast<float4*>(&As[c][p4]) =
                *reinterpret_cast<const float4*>(At + c * NPIX + pt + p4);
        }
#pragma unroll
        for (int i = 0; i < 4; i++) {
            int idx = t + (i << 8);
            int o = idx & 31;
            int c = idx >> 5;
            Wt[c][o] = Wout[(ot + o) * 768 + kt * 32 + c];
        }
        __syncthreads();
#pragma unroll
        for (int kk = 0; kk < 32; kk++) {
            float4 a = *reinterpret_cast<const float4*>(&As[kk][pc << 2]);
            float av[4] = {a.x, a.y, a.z, a.w};
            float4 b4 = *reinterpret_cast<const float4*>(&Wt[kk][oc << 2]);
            float bv[4] = {b4.x, b4.y, b4.z, b4.w};
#pragma unroll
            for (int j = 0; j < 4; j++)
#pragma unroll
                for (int i = 0; i < 4; i++)
                    acc[j][i] = fmaf(bv[j], av[i], acc[j][i]);
        }
        __syncthreads();
    }

#pragma unroll
    for (int j = 0; j < 4; j++) {
        const int o = ot + (oc << 2) + j;
        const float bb = bout[o];
        float4 r;
        r.x = acc[j][0] + bb;
        r.y = acc[j][1] + bb;
        r.z = acc[j][2] + bb;
        r.w = acc[j][3] + bb;
        *reinterpret_cast<float4*>(out + o * NPIX + pt + (pc << 2)) = r;
    }
}

extern "C" void kernel_launch(void* const* d_in, const int* in_sizes, int n_in,
                              void* d_out, int out_size, void* d_ws, size_t ws_size,
                              hipStream_t stream)
{
    const float* x    = (const float*)d_in[0];
    const float* Wq   = (const float*)d_in[1];
    const float* Wk   = (const float*)d_in[2];
    const float* Wv   = (const float*)d_in[3];
    const float* Wout = (const float*)d_in[4];
    const float* bout = (const float*)d_in[5];
    float* out = (float*)d_out;

    float* ws = (float*)d_ws;
    float* q = ws;
    float* k = ws + 1048576;
    float* v = ws + 2097152;
    float* A = ws;                    // aliases q/k/v (dead after attn)
    float* num = ws + 3145728;
    const size_t fl = ws_size / 4;

    qkv_kernel<<<dim3(32, 8, 3), 256, 0, stream>>>(x, Wq, Wk, Wv, q, k, v);

    if (fl >= 16121856) {             // NS = 4
        float* nrm = num + (size_t)4 * 3145728;
        attn_kernel<8><<<dim3(33, 8, 4), 256, 0, stream>>>(q, k, v, num, nrm);
        merge_kernel<4><<<dim3(4, 24), 256, 0, stream>>>(num, nrm, A);
    } else if (fl >= 9633792) {       // NS = 2
        float* nrm = num + (size_t)2 * 3145728;
        attn_kernel<16><<<dim3(33, 8, 2), 256, 0, stream>>>(q, k, v, num, nrm);
        merge_kernel<2><<<dim3(4, 24), 256, 0, stream>>>(num, nrm, A);
    } else {                          // NS = 1
        float* nrm = num + (size_t)3145728;
        attn_kernel<32><<<dim3(33, 8, 1), 256, 0, stream>>>(q, k, v, num, nrm);
        merge_kernel<1><<<dim3(4, 24), 256, 0, stream>>>(num, nrm, A);
    }

    out_kernel<<<dim3(32, 8), 256, 0, stream>>>(A, Wout, bout, out);
}